// Round 5
// baseline (306.669 us; speedup 1.0000x reference)
//
#include <hip/hip_runtime.h>

// MKGCN — R10: L3-prefetch probe. Ledger: R7 (+60% waves) null, R8 (deeper
// per-wave batching) ~null, R9 (perfect coalescing) regressed via scratch
// spill (WRITE_SIZE 64KB->39MB at VGPR=40) with service rate unchanged.
// FETCH ~161-180MB is within ~20% of compulsory unique working set; the
// ~2 TB/s line-service rate is pinned vs concurrency AND request shape.
// Remaining hypothesis: HBM is row-activation-bound serving unique 128B
// lines in RANDOM order. E = 128MB fits in the 256MB Infinity Cache, so a
// sequential sweep kernel (streams E at ~6.3TB/s, ~20us) converts the HBM
// traffic to streaming order; the unchanged main kernel's gathers then hit
// L3. Decisive either way: win -> order was the limit; null -> 4th
// orthogonal null => random-service roofline, declare next round.
// Main kernel = R8 verbatim (82.5us, absmax 0, no spill).

#define NT 256
#define WFENCE() asm volatile("" ::: "memory")

__device__ __forceinline__ float sigmoidf_(float x) { return 1.0f / (1.0f + __expf(-x)); }

// ---- prefetch sweep: stream E sequentially to populate Infinity Cache ----
__global__ __launch_bounds__(NT) void sweep_E(const float4* __restrict__ Ev, int n4) {
    int i = blockIdx.x * NT + threadIdx.x;
    const int stride = gridDim.x * NT;
    for (; i < n4; i += stride) {
        const float4 f = Ev[i];
        // keep the load live without any store (rule #17)
        asm volatile("" :: "v"(f.x), "v"(f.y), "v"(f.z), "v"(f.w));
    }
}

__global__ __launch_bounds__(NT, 6) void mkgcn_wpe(
    const int* __restrict__ users,
    const int* __restrict__ items,
    const float* __restrict__ E,      // [1e6, 32]
    const float* __restrict__ R,      // [60, 32]
    const int* __restrict__ adjE,     // [1e6, 16]
    const int* __restrict__ adjR,     // [1e6, 16]
    const int* __restrict__ uhist,    // [1e5, 16]
    const float* __restrict__ Wg,     // [32, 32]
    const float* __restrict__ bg,     // [32]
    float* __restrict__ out,          // [B]
    int B)
{
    struct PE {
        int   e2[256];      // transposed: e2[k*16+n]
        float attn[256];    // r2T (ints) early -> attn[k*16+n] after P4
        float v1[16][32];   // v1 -> x1 (P5) -> hv1 (P6)
        float ue[32];
        float sdot[64];     // 60 used
        float attn0[16];
        float x0[32];       // x0 (P7) -> x0' (P9)
    };                      // 4672 B; pe[4]=18688 + Wl 4096 = 22784 -> LDS 23040
    __shared__ __align__(16) float Wl[32][32];
    __shared__ __align__(16) PE pe[4];

    const int t = threadIdx.x;
    const int w = t >> 6;     // wave id
    const int L = t & 63;     // lane
    int b = blockIdx.x * 4 + w;
    if (b >= B) b = B - 1;    // tail clamp: duplicate compute, same value written
    PE& P = pe[w];

    const int user = users[b];
    const int item = items[b];

    // ---- P0: index rows (regs), v0 (regs), W, b (reg) ----
    int hid = 0, e1v = 0, r1v = 0;
    float v0r = 0.f;
    if (L < 16)       hid = uhist[(long)user * 16 + L];
    else if (L < 32)  e1v = adjE[(long)item * 16 + (L - 16)];
    else if (L < 48)  r1v = adjR[(long)item * 16 + (L - 32)];
    if (L < 32)       v0r = E[(long)item * 32 + L];
    ((float4*)Wl)[t] = ((const float4*)Wg)[t];
    const float bv = bg[L & 31];

    const int v  = L & 7;     // float4 index within row
    const int r8 = L >> 3;    // row group 0..7

    // ---- P1: history mean (register reduce), hop-2 adjacency (transposed), v1 ----
    {
        const int h0i = __shfl(hid, r8);
        const int h1i = __shfl(hid, r8 + 8);
        const float4 a = ((const float4*)(E + (long)h0i * 32))[v];
        const float4 c = ((const float4*)(E + (long)h1i * 32))[v];
        float sx = a.x + c.x, sy = a.y + c.y, sz = a.z + c.z, sw = a.w + c.w;
        #pragma unroll
        for (int off = 8; off < 64; off <<= 1) {
            sx += __shfl_xor(sx, off); sy += __shfl_xor(sy, off);
            sz += __shfl_xor(sz, off); sw += __shfl_xor(sw, off);
        }
        if (L < 8) {   // lane L has v == L here
            float4 u; u.x = sx * 0.0625f; u.y = sy * 0.0625f;
            u.z = sz * 0.0625f; u.w = sw * 0.0625f;
            ((float4*)P.ue)[L] = u;
        }
    }
    {
        const int n = L >> 2, c4 = L & 3;
        const int e1n = __shfl(e1v, 16 + n);
        const int4 ev = ((const int4*)(adjE + (long)e1n * 16))[c4];
        const int4 rv = ((const int4*)(adjR + (long)e1n * 16))[c4];
        int* r2Ti = (int*)P.attn;           // park r2T in attn buffer (dead until P4)
        P.e2[(c4 * 4 + 0) * 16 + n] = ev.x;  P.e2[(c4 * 4 + 1) * 16 + n] = ev.y;
        P.e2[(c4 * 4 + 2) * 16 + n] = ev.z;  P.e2[(c4 * 4 + 3) * 16 + n] = ev.w;
        r2Ti[(c4 * 4 + 0) * 16 + n] = rv.x;  r2Ti[(c4 * 4 + 1) * 16 + n] = rv.y;
        r2Ti[(c4 * 4 + 2) * 16 + n] = rv.z;  r2Ti[(c4 * 4 + 3) * 16 + n] = rv.w;
    }
    #pragma unroll
    for (int it = 0; it < 2; ++it) {
        const int r = r8 + 8 * it;
        const int e1r = __shfl(e1v, 16 + r);
        ((float4*)P.v1)[r * 8 + v] = ((const float4*)(E + (long)e1r * 32))[v];
    }
    WFENCE();   // ue, e2, r2T, v1 ready (wave-private)

    // ---- P3: sdot[r] = dot(ue, R[r]) ----
    if (L < 60) {
        const float4* rr = (const float4*)(R + L * 32);
        const float4* uu = (const float4*)P.ue;
        float s = 0.f;
        #pragma unroll
        for (int j = 0; j < 8; ++j) {
            const float4 a = rr[j], u = uu[j];
            s += a.x * u.x + a.y * u.y + a.z * u.z + a.w * u.w;
        }
        P.sdot[L] = s;
    }
    WFENCE();   // sdot ready

    // ---- P4: softmax attention, in place over r2T (each slot owned by one lane) ----
    {
        const int* r2T = (const int*)P.attn;
        #pragma unroll
        for (int c = 0; c < 4; ++c) {
            const int k = L & 15, n = c * 4 + (L >> 4);
            const float s = P.sdot[r2T[k * 16 + n]];
            float m = s;
            #pragma unroll
            for (int off = 1; off < 16; off <<= 1) m = fmaxf(m, __shfl_xor(m, off, 16));
            const float e = __expf(s - m);
            float sum = e;
            #pragma unroll
            for (int off = 1; off < 16; off <<= 1) sum += __shfl_xor(sum, off, 16);
            P.attn[k * 16 + n] = e / sum;
        }
    }
    const int r1L = __shfl(r1v, 32 + (L & 15));   // hoisted: sources lanes 32..47
    if (L < 16) {
        const float s = P.sdot[r1L];
        float m = s;
        #pragma unroll
        for (int off = 1; off < 16; off <<= 1) m = fmaxf(m, __shfl_xor(m, off, 16));
        const float e = __expf(s - m);
        float sum = e;
        #pragma unroll
        for (int off = 1; off < 16; off <<= 1) sum += __shfl_xor(sum, off, 16);
        P.attn0[L] = e / sum;
    }
    WFENCE();   // attn, attn0 ready; r2T dead

    // ---- P7 (hoisted): item aggregation over ORIGINAL v1, before P5 overwrites ----
    if (L < 32) {
        float a = 0.f;
        #pragma unroll
        for (int k = 0; k < 16; ++k) a += P.attn0[k] * P.v1[k][L];
        P.x0[L] = v0r + a;
    }
    WFENCE();   // all v1 reads ordered before P5's in-place writes

    // ---- P5: hop-2 weighted gather, explicit MLP chunks. x1 overwrites v1 ----
    {
        const int n  = L >> 2;
        const int s0 = (L & 3) * 2;
        float ax0 = 0, ay0 = 0, az0 = 0, aw0 = 0;
        float ax1 = 0, ay1 = 0, az1 = 0, aw1 = 0;
        #pragma unroll
        for (int kc = 0; kc < 4; ++kc) {
            // (a) batch LDS reads: 4 indices + 4 weights into regs
            int   rowi[4];
            float awt[4];
            #pragma unroll
            for (int j = 0; j < 4; ++j) {
                rowi[j] = P.e2[(kc * 4 + j) * 16 + n];     // conflict-free broadcast
                awt[j]  = P.attn[(kc * 4 + j) * 16 + n];
            }
            // (b) issue all 8 global float4 loads (statically-indexed regs)
            float4 f[8];
            #pragma unroll
            for (int j = 0; j < 4; ++j) {
                const float4* er = (const float4*)(E + (long)rowi[j] * 32);
                f[2 * j]     = er[s0];
                f[2 * j + 1] = er[s0 + 1];
            }
            // (c) consume, k ascending (same FMA order as before -> bit-identical)
            #pragma unroll
            for (int j = 0; j < 4; ++j) {
                const float aw = awt[j];
                ax0 += aw * f[2 * j].x;     ay0 += aw * f[2 * j].y;
                az0 += aw * f[2 * j].z;     aw0 += aw * f[2 * j].w;
                ax1 += aw * f[2 * j + 1].x; ay1 += aw * f[2 * j + 1].y;
                az1 += aw * f[2 * j + 1].z; aw1 += aw * f[2 * j + 1].w;
            }
        }
        const float4 va = ((const float4*)P.v1)[n * 8 + s0];
        const float4 vb = ((const float4*)P.v1)[n * 8 + s0 + 1];
        float4 xa, xb;
        xa.x = va.x + ax0; xa.y = va.y + ay0; xa.z = va.z + az0; xa.w = va.w + aw0;
        xb.x = vb.x + ax1; xb.y = vb.y + ay1; xb.z = vb.z + az1; xb.w = vb.w + aw1;
        ((float4*)P.v1)[n * 8 + s0]     = xa;
        ((float4*)P.v1)[n * 8 + s0 + 1] = xb;
    }

    __syncthreads();   // ONLY block barrier: Wl visibility (cross-wave); x1 complete

    // ---- P6: hop-1 matvec + sigmoid; hv1 overwrites x1 in place ----
    const int dp = L & 31, half = L >> 5;
    {
        float hv[8];
        #pragma unroll
        for (int p = 0; p < 8; ++p) {
            const int n = p * 2 + half;
            float acc = bv;
            const float4* xr = (const float4*)P.v1[n];   // broadcast reads
            #pragma unroll
            for (int d4 = 0; d4 < 8; ++d4) {
                const float4 xv = xr[d4];
                acc += xv.x * Wl[d4 * 4 + 0][dp];
                acc += xv.y * Wl[d4 * 4 + 1][dp];
                acc += xv.z * Wl[d4 * 4 + 2][dp];
                acc += xv.w * Wl[d4 * 4 + 3][dp];
            }
            hv[p] = sigmoidf_(acc);
        }
        WFENCE();      // all reads ordered before in-place writes
        #pragma unroll
        for (int p = 0; p < 8; ++p) P.v1[p * 2 + half][dp] = hv[p];
    }
    WFENCE();   // hv1 ready

    // ---- P8: item matvec + sigmoid; h0 stays in a register ----
    float h0r = 0.f;
    if (L < 32) {
        float acc = bv;
        const float4* xr = (const float4*)P.x0;
        #pragma unroll
        for (int d4 = 0; d4 < 8; ++d4) {
            const float4 xv = xr[d4];
            acc += xv.x * Wl[d4 * 4 + 0][L];
            acc += xv.y * Wl[d4 * 4 + 1][L];
            acc += xv.z * Wl[d4 * 4 + 2][L];
            acc += xv.w * Wl[d4 * 4 + 3][L];
        }
        h0r = sigmoidf_(acc);
    }
    WFENCE();   // x0 reads ordered before P9's in-place write

    // ---- P9: iteration-1 aggregation (same attn0) over hv1; x0' over x0 ----
    if (L < 32) {
        float a = 0.f;
        #pragma unroll
        for (int k = 0; k < 16; ++k) a += P.attn0[k] * P.v1[k][L];
        P.x0[L] = h0r + a;
    }
    WFENCE();   // x0' ready

    // ---- P10: final matvec + tanh, dot(ue), sigmoid ----
    if (L < 32) {
        float acc = bv;
        const float4* xr = (const float4*)P.x0;
        #pragma unroll
        for (int d4 = 0; d4 < 8; ++d4) {
            const float4 xv = xr[d4];
            acc += xv.x * Wl[d4 * 4 + 0][L];
            acc += xv.y * Wl[d4 * 4 + 1][L];
            acc += xv.z * Wl[d4 * 4 + 2][L];
            acc += xv.w * Wl[d4 * 4 + 3][L];
        }
        const float ie = tanhf(acc);
        float pr = P.ue[L] * ie;
        #pragma unroll
        for (int off = 1; off < 32; off <<= 1) pr += __shfl_xor(pr, off, 32);
        if (L == 0) out[b] = sigmoidf_(pr);
    }
}

extern "C" void kernel_launch(void* const* d_in, const int* in_sizes, int n_in,
                              void* d_out, int out_size, void* d_ws, size_t ws_size,
                              hipStream_t stream) {
    const int* users   = (const int*)d_in[0];
    const int* items   = (const int*)d_in[1];
    const float* E     = (const float*)d_in[2];
    const float* R     = (const float*)d_in[3];
    const int* adjE    = (const int*)d_in[4];
    const int* adjR    = (const int*)d_in[5];
    const int* uhist   = (const int*)d_in[6];
    const float* Wg    = (const float*)d_in[7];
    const float* bg    = (const float*)d_in[8];
    float* out         = (float*)d_out;

    const int B = in_sizes[0];

    // Phase 0: stream E (128 MB) sequentially -> Infinity Cache resident,
    // converting the main kernel's E-misses from random-order HBM to L3 hits.
    const int n4 = 1000000 * 32 / 4;   // E in float4s
    sweep_E<<<2048, NT, 0, stream>>>((const float4*)E, n4);

    const int grid = (B + 3) / 4;
    mkgcn_wpe<<<grid, NT, 0, stream>>>(users, items, E, R, adjE, adjR, uhist, Wg, bg, out, B);
}

// Round 6
// 283.608 us; speedup vs baseline: 1.0813x; 1.0813x over previous
//
#include <hip/hip_runtime.h>

// MKGCN — R11: revert to R8 (best verified: 82.5us dispatch / 281.5us bench),
// sweep dropped. Probe ledger (all on the hop-2 random gather, the kernel's
// cost center):
//   R7  waves/CU +60%            -> null   (service pinned ~1.95 TB/s)
//   R8  explicit 8-deep batching -> ~null  (-2%)
//   R9  full-line coalescing     -> regression (VGPR spill at cap 40)
//   R10 IC-warm via E-sweep      -> main -8.5us but sweep +17us; bounds the
//       random-128B service path at ~2.6 TB/s even when IC-resident.
// FETCH 161-180MB vs ~134MB compulsory unique working set; random-line
// service ~2.2 TB/s ~= 1/3 of measured streaming rate (6.9-7.5 TB/s) = the
// canonical random-gather ceiling. 161MB/2.2TB/s ~= 73us irreducible vs
// 82.5us achieved -> structural floor reached for this formulation.

#define NT 256
#define WFENCE() asm volatile("" ::: "memory")

__device__ __forceinline__ float sigmoidf_(float x) { return 1.0f / (1.0f + __expf(-x)); }

__global__ __launch_bounds__(NT, 6) void mkgcn_wpe(
    const int* __restrict__ users,
    const int* __restrict__ items,
    const float* __restrict__ E,      // [1e6, 32]
    const float* __restrict__ R,      // [60, 32]
    const int* __restrict__ adjE,     // [1e6, 16]
    const int* __restrict__ adjR,     // [1e6, 16]
    const int* __restrict__ uhist,    // [1e5, 16]
    const float* __restrict__ Wg,     // [32, 32]
    const float* __restrict__ bg,     // [32]
    float* __restrict__ out,          // [B]
    int B)
{
    struct PE {
        int   e2[256];      // transposed: e2[k*16+n]
        float attn[256];    // r2T (ints) early -> attn[k*16+n] after P4
        float v1[16][32];   // v1 -> x1 (P5) -> hv1 (P6)
        float ue[32];
        float sdot[64];     // 60 used
        float attn0[16];
        float x0[32];       // x0 (P7) -> x0' (P9)
    };                      // 4672 B; pe[4]=18688 + Wl 4096 = 22784 -> LDS 23040
    __shared__ __align__(16) float Wl[32][32];
    __shared__ __align__(16) PE pe[4];

    const int t = threadIdx.x;
    const int w = t >> 6;     // wave id
    const int L = t & 63;     // lane
    int b = blockIdx.x * 4 + w;
    if (b >= B) b = B - 1;    // tail clamp: duplicate compute, same value written
    PE& P = pe[w];

    const int user = users[b];
    const int item = items[b];

    // ---- P0: index rows (regs), v0 (regs), W, b (reg) ----
    int hid = 0, e1v = 0, r1v = 0;
    float v0r = 0.f;
    if (L < 16)       hid = uhist[(long)user * 16 + L];
    else if (L < 32)  e1v = adjE[(long)item * 16 + (L - 16)];
    else if (L < 48)  r1v = adjR[(long)item * 16 + (L - 32)];
    if (L < 32)       v0r = E[(long)item * 32 + L];
    ((float4*)Wl)[t] = ((const float4*)Wg)[t];
    const float bv = bg[L & 31];

    const int v  = L & 7;     // float4 index within row
    const int r8 = L >> 3;    // row group 0..7

    // ---- P1: history mean (register reduce), hop-2 adjacency (transposed), v1 ----
    {
        const int h0i = __shfl(hid, r8);
        const int h1i = __shfl(hid, r8 + 8);
        const float4 a = ((const float4*)(E + (long)h0i * 32))[v];
        const float4 c = ((const float4*)(E + (long)h1i * 32))[v];
        float sx = a.x + c.x, sy = a.y + c.y, sz = a.z + c.z, sw = a.w + c.w;
        #pragma unroll
        for (int off = 8; off < 64; off <<= 1) {
            sx += __shfl_xor(sx, off); sy += __shfl_xor(sy, off);
            sz += __shfl_xor(sz, off); sw += __shfl_xor(sw, off);
        }
        if (L < 8) {   // lane L has v == L here
            float4 u; u.x = sx * 0.0625f; u.y = sy * 0.0625f;
            u.z = sz * 0.0625f; u.w = sw * 0.0625f;
            ((float4*)P.ue)[L] = u;
        }
    }
    {
        const int n = L >> 2, c4 = L & 3;
        const int e1n = __shfl(e1v, 16 + n);
        const int4 ev = ((const int4*)(adjE + (long)e1n * 16))[c4];
        const int4 rv = ((const int4*)(adjR + (long)e1n * 16))[c4];
        int* r2Ti = (int*)P.attn;           // park r2T in attn buffer (dead until P4)
        P.e2[(c4 * 4 + 0) * 16 + n] = ev.x;  P.e2[(c4 * 4 + 1) * 16 + n] = ev.y;
        P.e2[(c4 * 4 + 2) * 16 + n] = ev.z;  P.e2[(c4 * 4 + 3) * 16 + n] = ev.w;
        r2Ti[(c4 * 4 + 0) * 16 + n] = rv.x;  r2Ti[(c4 * 4 + 1) * 16 + n] = rv.y;
        r2Ti[(c4 * 4 + 2) * 16 + n] = rv.z;  r2Ti[(c4 * 4 + 3) * 16 + n] = rv.w;
    }
    #pragma unroll
    for (int it = 0; it < 2; ++it) {
        const int r = r8 + 8 * it;
        const int e1r = __shfl(e1v, 16 + r);
        ((float4*)P.v1)[r * 8 + v] = ((const float4*)(E + (long)e1r * 32))[v];
    }
    WFENCE();   // ue, e2, r2T, v1 ready (wave-private)

    // ---- P3: sdot[r] = dot(ue, R[r]) ----
    if (L < 60) {
        const float4* rr = (const float4*)(R + L * 32);
        const float4* uu = (const float4*)P.ue;
        float s = 0.f;
        #pragma unroll
        for (int j = 0; j < 8; ++j) {
            const float4 a = rr[j], u = uu[j];
            s += a.x * u.x + a.y * u.y + a.z * u.z + a.w * u.w;
        }
        P.sdot[L] = s;
    }
    WFENCE();   // sdot ready

    // ---- P4: softmax attention, in place over r2T (each slot owned by one lane) ----
    {
        const int* r2T = (const int*)P.attn;
        #pragma unroll
        for (int c = 0; c < 4; ++c) {
            const int k = L & 15, n = c * 4 + (L >> 4);
            const float s = P.sdot[r2T[k * 16 + n]];
            float m = s;
            #pragma unroll
            for (int off = 1; off < 16; off <<= 1) m = fmaxf(m, __shfl_xor(m, off, 16));
            const float e = __expf(s - m);
            float sum = e;
            #pragma unroll
            for (int off = 1; off < 16; off <<= 1) sum += __shfl_xor(sum, off, 16);
            P.attn[k * 16 + n] = e / sum;
        }
    }
    const int r1L = __shfl(r1v, 32 + (L & 15));   // hoisted: sources lanes 32..47
    if (L < 16) {
        const float s = P.sdot[r1L];
        float m = s;
        #pragma unroll
        for (int off = 1; off < 16; off <<= 1) m = fmaxf(m, __shfl_xor(m, off, 16));
        const float e = __expf(s - m);
        float sum = e;
        #pragma unroll
        for (int off = 1; off < 16; off <<= 1) sum += __shfl_xor(sum, off, 16);
        P.attn0[L] = e / sum;
    }
    WFENCE();   // attn, attn0 ready; r2T dead

    // ---- P7 (hoisted): item aggregation over ORIGINAL v1, before P5 overwrites ----
    if (L < 32) {
        float a = 0.f;
        #pragma unroll
        for (int k = 0; k < 16; ++k) a += P.attn0[k] * P.v1[k][L];
        P.x0[L] = v0r + a;
    }
    WFENCE();   // all v1 reads ordered before P5's in-place writes

    // ---- P5: hop-2 weighted gather, explicit MLP chunks. x1 overwrites v1 ----
    {
        const int n  = L >> 2;
        const int s0 = (L & 3) * 2;
        float ax0 = 0, ay0 = 0, az0 = 0, aw0 = 0;
        float ax1 = 0, ay1 = 0, az1 = 0, aw1 = 0;
        #pragma unroll
        for (int kc = 0; kc < 4; ++kc) {
            // (a) batch LDS reads: 4 indices + 4 weights into regs
            int   rowi[4];
            float awt[4];
            #pragma unroll
            for (int j = 0; j < 4; ++j) {
                rowi[j] = P.e2[(kc * 4 + j) * 16 + n];     // conflict-free broadcast
                awt[j]  = P.attn[(kc * 4 + j) * 16 + n];
            }
            // (b) issue all 8 global float4 loads (statically-indexed regs)
            float4 f[8];
            #pragma unroll
            for (int j = 0; j < 4; ++j) {
                const float4* er = (const float4*)(E + (long)rowi[j] * 32);
                f[2 * j]     = er[s0];
                f[2 * j + 1] = er[s0 + 1];
            }
            // (c) consume, k ascending (same FMA order as before -> bit-identical)
            #pragma unroll
            for (int j = 0; j < 4; ++j) {
                const float aw = awt[j];
                ax0 += aw * f[2 * j].x;     ay0 += aw * f[2 * j].y;
                az0 += aw * f[2 * j].z;     aw0 += aw * f[2 * j].w;
                ax1 += aw * f[2 * j + 1].x; ay1 += aw * f[2 * j + 1].y;
                az1 += aw * f[2 * j + 1].z; aw1 += aw * f[2 * j + 1].w;
            }
        }
        const float4 va = ((const float4*)P.v1)[n * 8 + s0];
        const float4 vb = ((const float4*)P.v1)[n * 8 + s0 + 1];
        float4 xa, xb;
        xa.x = va.x + ax0; xa.y = va.y + ay0; xa.z = va.z + az0; xa.w = va.w + aw0;
        xb.x = vb.x + ax1; xb.y = vb.y + ay1; xb.z = vb.z + az1; xb.w = vb.w + aw1;
        ((float4*)P.v1)[n * 8 + s0]     = xa;
        ((float4*)P.v1)[n * 8 + s0 + 1] = xb;
    }

    __syncthreads();   // ONLY block barrier: Wl visibility (cross-wave); x1 complete

    // ---- P6: hop-1 matvec + sigmoid; hv1 overwrites x1 in place ----
    const int dp = L & 31, half = L >> 5;
    {
        float hv[8];
        #pragma unroll
        for (int p = 0; p < 8; ++p) {
            const int n = p * 2 + half;
            float acc = bv;
            const float4* xr = (const float4*)P.v1[n];   // broadcast reads
            #pragma unroll
            for (int d4 = 0; d4 < 8; ++d4) {
                const float4 xv = xr[d4];
                acc += xv.x * Wl[d4 * 4 + 0][dp];
                acc += xv.y * Wl[d4 * 4 + 1][dp];
                acc += xv.z * Wl[d4 * 4 + 2][dp];
                acc += xv.w * Wl[d4 * 4 + 3][dp];
            }
            hv[p] = sigmoidf_(acc);
        }
        WFENCE();      // all reads ordered before in-place writes
        #pragma unroll
        for (int p = 0; p < 8; ++p) P.v1[p * 2 + half][dp] = hv[p];
    }
    WFENCE();   // hv1 ready

    // ---- P8: item matvec + sigmoid; h0 stays in a register ----
    float h0r = 0.f;
    if (L < 32) {
        float acc = bv;
        const float4* xr = (const float4*)P.x0;
        #pragma unroll
        for (int d4 = 0; d4 < 8; ++d4) {
            const float4 xv = xr[d4];
            acc += xv.x * Wl[d4 * 4 + 0][L];
            acc += xv.y * Wl[d4 * 4 + 1][L];
            acc += xv.z * Wl[d4 * 4 + 2][L];
            acc += xv.w * Wl[d4 * 4 + 3][L];
        }
        h0r = sigmoidf_(acc);
    }
    WFENCE();   // x0 reads ordered before P9's in-place write

    // ---- P9: iteration-1 aggregation (same attn0) over hv1; x0' over x0 ----
    if (L < 32) {
        float a = 0.f;
        #pragma unroll
        for (int k = 0; k < 16; ++k) a += P.attn0[k] * P.v1[k][L];
        P.x0[L] = h0r + a;
    }
    WFENCE();   // x0' ready

    // ---- P10: final matvec + tanh, dot(ue), sigmoid ----
    if (L < 32) {
        float acc = bv;
        const float4* xr = (const float4*)P.x0;
        #pragma unroll
        for (int d4 = 0; d4 < 8; ++d4) {
            const float4 xv = xr[d4];
            acc += xv.x * Wl[d4 * 4 + 0][L];
            acc += xv.y * Wl[d4 * 4 + 1][L];
            acc += xv.z * Wl[d4 * 4 + 2][L];
            acc += xv.w * Wl[d4 * 4 + 3][L];
        }
        const float ie = tanhf(acc);
        float pr = P.ue[L] * ie;
        #pragma unroll
        for (int off = 1; off < 32; off <<= 1) pr += __shfl_xor(pr, off, 32);
        if (L == 0) out[b] = sigmoidf_(pr);
    }
}

extern "C" void kernel_launch(void* const* d_in, const int* in_sizes, int n_in,
                              void* d_out, int out_size, void* d_ws, size_t ws_size,
                              hipStream_t stream) {
    const int* users   = (const int*)d_in[0];
    const int* items   = (const int*)d_in[1];
    const float* E     = (const float*)d_in[2];
    const float* R     = (const float*)d_in[3];
    const int* adjE    = (const int*)d_in[4];
    const int* adjR    = (const int*)d_in[5];
    const int* uhist   = (const int*)d_in[6];
    const float* Wg    = (const float*)d_in[7];
    const float* bg    = (const float*)d_in[8];
    float* out         = (float*)d_out;

    const int B = in_sizes[0];
    const int grid = (B + 3) / 4;
    mkgcn_wpe<<<grid, NT, 0, stream>>>(users, items, E, R, adjE, adjR, uhist, Wg, bg, out, B);
}